// Round 10
// baseline (270.592 us; speedup 1.0000x reference)
//
#include <hip/hip_runtime.h>
#include <math.h>

// ADIOS contrastive loss, MI355X — fp16 MFMA (K=512), persistent col-group GEMM.
// Each block: one 128-row A panel x 640 cols (5 col-tiles) in ONE flattened
// 80-step double-buffered pipeline (counted vmcnt(4), 2 raw barriers/step).
// Epilogue (exp/denom/pos) of tile i overlaps stages of tile i+1.
// memset folded into prep (zero-block); loss folded into gemm (ticket).

#define B_ROWS 4096
#define M_MASK 4
#define D_DIM  512
#define N_COLS ((M_MASK + 1) * B_ROWS)   // 20480
#define GK     D_DIM                     // 512 fp16
#define NT     16                        // K-tiles per col-tile (512/32)
#define TPB    5                         // col-tiles per block
#define STEPS  (NT * TPB)                // 80
#define NGROUPS 32
#define CHUNK  (N_COLS / NGROUPS)        // 640

typedef _Float16 f16x8 __attribute__((ext_vector_type(8)));
typedef float    f32x4 __attribute__((ext_vector_type(4)));

__device__ __forceinline__ float inv_temp(const int* __restrict__ itp) {
    int it = *itp;
    double T;
    if (it >= 300000) {
        T = 0.05;
    } else {
        double p = (double)it / 300000.0;
        T = 0.05 + 0.5 * (0.2 - 0.05) * (1.0 + cos(3.14159265358979323846 * p));
    }
    return (float)(1.0 / T);
}

// One wave per row: L2-normalize, cast fp16, store [N_COLS][GK].
// Extra block (blockIdx == N_COLS/4) zeroes denom/pos/ticket.
__global__ __launch_bounds__(256) void prep_kernel(
        const float* __restrict__ orig, const float* __restrict__ masked,
        _Float16* __restrict__ E, float* __restrict__ zbuf, int* __restrict__ ticket) {
    if (blockIdx.x == N_COLS / 4) {
        float4 z = {0.f, 0.f, 0.f, 0.f};
        #pragma unroll
        for (int i = 0; i < 8; ++i)
            *(float4*)(zbuf + threadIdx.x * 4 + i * 1024) = z;  // 8192 floats total
        if (threadIdx.x == 0) *ticket = 0;
        return;
    }
    int gw = blockIdx.x * 4 + (threadIdx.x >> 6);
    int l  = threadIdx.x & 63;
    const float* row = (gw < B_ROWS) ? orig + (size_t)gw * D_DIM
                                     : masked + (size_t)(gw - B_ROWS) * D_DIM;
    float4 a = *(const float4*)(row + l * 8);
    float4 b = *(const float4*)(row + l * 8 + 4);
    float s = a.x*a.x + a.y*a.y + a.z*a.z + a.w*a.w
            + b.x*b.x + b.y*b.y + b.z*b.z + b.w*b.w;
    #pragma unroll
    for (int off = 1; off < 64; off <<= 1) s += __shfl_xor(s, off, 64);
    float inv = 1.0f / fmaxf(sqrtf(s), 1e-12f);

    f16x8 h;
    h[0] = (_Float16)(a.x*inv); h[1] = (_Float16)(a.y*inv);
    h[2] = (_Float16)(a.z*inv); h[3] = (_Float16)(a.w*inv);
    h[4] = (_Float16)(b.x*inv); h[5] = (_Float16)(b.y*inv);
    h[6] = (_Float16)(b.z*inv); h[7] = (_Float16)(b.w*inv);
    *(f16x8*)(E + (size_t)gw * GK + l * 8) = h;
}

// 128x128 tiles, 4 waves (2x2), 5 col-tiles per block, fused exp/denom/pos,
// last block computes the final loss.
__global__ __launch_bounds__(256, 5) void gemm_kernel(
        const _Float16* __restrict__ E, const int* __restrict__ itp,
        float* __restrict__ denom, float* __restrict__ pos,
        int* __restrict__ ticket, float* __restrict__ out) {
    __shared__ _Float16 LDS[2 * 8192];   // 32 KiB: 2 slots of (A[128][32] | B[128][32])

    const int tid = threadIdx.x;
    const int l   = tid & 63;
    const int wid = tid >> 6;
    const int wr  = wid >> 1;
    const int wc  = wid & 1;

    const int rowTile  = blockIdx.x & 31;          // consecutive bids share col-group
    const int group    = blockIdx.x >> 5;
    const int rowBase  = rowTile * 128;
    const int colStart = group * CHUNK;

    const _Float16* Ag = E + (size_t)rowBase * GK;

    // Stage step s: col-tile s/16, K-tile s%16 -> slot s&1 (A 8KB + B 8KB).
    auto STAGE = [&](int s) {
        _Float16* base = LDS + (s & 1) * 8192;
        const int kb = (s & 15) * 32;
        const _Float16* Bg = E + (size_t)(colStart + (s >> 4) * 128) * GK;
        #pragma unroll
        for (int i = 0; i < 2; ++i) {
            const int rc = wid * 32 + i * 16;
            const int r  = rc + (l >> 2);
            const size_t go = (size_t)r * GK + kb + (l & 3) * 8;
            __builtin_amdgcn_global_load_lds(
                (const __attribute__((address_space(1))) void*)(Ag + go),
                (__attribute__((address_space(3))) void*)(base + rc * 32), 16, 0, 0);
            __builtin_amdgcn_global_load_lds(
                (const __attribute__((address_space(1))) void*)(Bg + go),
                (__attribute__((address_space(3))) void*)(base + 4096 + rc * 32), 16, 0, 0);
        }
    };

    f16x8 af[4], bf[4];
    auto FRAGS = [&](int s) {
        const _Float16* base = LDS + (s & 1) * 8192;
        #pragma unroll
        for (int m = 0; m < 4; ++m)
            af[m] = *(const f16x8*)(base + (wr * 64 + m * 16 + (l & 15)) * 32 + (l >> 4) * 8);
        #pragma unroll
        for (int n = 0; n < 4; ++n)
            bf[n] = *(const f16x8*)(base + 4096 + (wc * 64 + n * 16 + (l & 15)) * 32 + (l >> 4) * 8);
    };

    f32x4 acc[4][4];
    #pragma unroll
    for (int m = 0; m < 4; ++m)
        #pragma unroll
        for (int n = 0; n < 4; ++n)
            #pragma unroll
            for (int j = 0; j < 4; ++j) acc[m][n][j] = 0.f;

    const float scale = inv_temp(itp) * 1.44269504088896340736f;  // exp2

#define BAR()   __builtin_amdgcn_s_barrier()
#define LGKM0() { asm volatile("s_waitcnt lgkmcnt(0)" ::: "memory"); \
                  __builtin_amdgcn_sched_barrier(0); }

    STAGE(0);
    #pragma unroll 2
    for (int s = 0; s < STEPS; ++s) {
        if (s + 1 < STEPS) {
            STAGE(s + 1);
            asm volatile("s_waitcnt vmcnt(4)" ::: "memory");  // tile s complete
        } else {
            asm volatile("s_waitcnt vmcnt(0)" ::: "memory");
        }
        BAR();              // all waves' tile-s writes visible
        FRAGS(s);
        LGKM0();
        __builtin_amdgcn_s_setprio(1);
        #pragma unroll
        for (int m = 0; m < 4; ++m)
            #pragma unroll
            for (int n = 0; n < 4; ++n)
                acc[m][n] = __builtin_amdgcn_mfma_f32_16x16x32_f16(af[m], bf[n], acc[m][n], 0, 0, 0);
        __builtin_amdgcn_s_setprio(0);
        BAR();              // readers drained (LGKM0 above) before next overwrite

        if ((s & 15) == 15) {
            // Epilogue for col-tile ct (overlaps next tile's in-flight stages).
            const int ct = s >> 4;
            const int colBase = colStart + ct * 128;
            float dsum[16];
            #pragma unroll
            for (int i = 0; i < 16; ++i) dsum[i] = 0.f;
            #pragma unroll
            for (int m = 0; m < 4; ++m) {
                #pragma unroll
                for (int n = 0; n < 4; ++n) {
                    const int col = colBase + wc * 64 + n * 16 + (l & 15);
                    #pragma unroll
                    for (int r = 0; r < 4; ++r) {
                        const int row = rowBase + wr * 64 + m * 16 + (l >> 4) * 4 + r;
                        float e = exp2f(acc[m][n][r] * scale);
                        if (col == row) e = 0.f;
                        dsum[m * 4 + r] += e;
                        const int d = col - row;
                        if (d > 0 && (d & (B_ROWS - 1)) == 0) atomicAdd(&pos[row], e);
                        acc[m][n][r] = 0.f;   // reset for next col-tile
                    }
                }
            }
            #pragma unroll
            for (int i = 0; i < 16; ++i) {
                #pragma unroll
                for (int off = 1; off < 16; off <<= 1)
                    dsum[i] += __shfl_xor(dsum[i], off, 64);
            }
            if ((l & 15) == 0) {
                #pragma unroll
                for (int i = 0; i < 16; ++i) {
                    const int row = rowBase + wr * 64 + (i >> 2) * 16 + (l >> 4) * 4 + (i & 3);
                    atomicAdd(&denom[row], dsum[i]);
                }
            }
        }
    }
#undef BAR
#undef LGKM0

    // Last block computes the loss (all contributions fenced via ticket).
    __shared__ int lastFlag;
    if (tid == 0) {
        __threadfence();
        lastFlag = (atomicAdd(ticket, 1) == (int)gridDim.x - 1) ? 1 : 0;
    }
    __syncthreads();
    if (lastFlag) {
        double s = 0.0;
        for (int i = tid; i < B_ROWS; i += 256) {
            float p = atomicAdd(&pos[i], 0.0f);     // device-coherent read
            float d = atomicAdd(&denom[i], 0.0f);
            s += (double)(-logf(p / (d + 1e-8f)));
        }
        double* buf = (double*)LDS;
        buf[tid] = s;
        __syncthreads();
        for (int off = 128; off >= 1; off >>= 1) {
            if (tid < off) buf[tid] += buf[tid + off];
            __syncthreads();
        }
        if (tid == 0) out[0] = (float)(buf[0] / (double)B_ROWS);
    }
}

extern "C" void kernel_launch(void* const* d_in, const int* in_sizes, int n_in,
                              void* d_out, int out_size, void* d_ws, size_t ws_size,
                              hipStream_t stream) {
    const float* orig   = (const float*)d_in[0];   // [B, D]
    const float* masked = (const float*)d_in[1];   // [M, B, D]
    const int*   itp    = (const int*)d_in[2];     // [1]

    _Float16* E   = (_Float16*)d_ws;                       // [N_COLS][GK] ~20 MB
    float* denom  = (float*)(E + (size_t)N_COLS * GK);     // [B]
    float* pos    = denom + B_ROWS;                        // [B]
    int*   ticket = (int*)(pos + B_ROWS);
    float* out    = (float*)d_out;

    prep_kernel<<<N_COLS / 4 + 1, 256, 0, stream>>>(orig, masked, E, denom, ticket);

    gemm_kernel<<<NGROUPS * (B_ROWS / 128), 256, 0, stream>>>(E, itp, denom, pos, ticket, out);
}